// Round 1
// baseline (353.948 us; speedup 1.0000x reference)
//
#include <hip/hip_runtime.h>
#include <hip/hip_bf16.h>

#define BH   512
#define NW   256
#define CC   128
#define NHEAD 4
#define HD   32
#define TOK  (BH * NW)   // 131072 tokens per side

typedef __attribute__((ext_vector_type(8))) short short8;
typedef __attribute__((ext_vector_type(4))) float f32x4;
typedef __attribute__((ext_vector_type(4))) int   i32x4;
typedef unsigned short ushort_t;

static __device__ __forceinline__ f32x4 mfma16(short8 a, short8 b, f32x4 c) {
    return __builtin_amdgcn_mfma_f32_16x16x32_bf16(a, b, c, 0, 0, 0);
}

// float -> bf16 bits, round-to-nearest-even
static __device__ __forceinline__ ushort_t f2bf(float f) {
    unsigned int u = __float_as_uint(f);
    u = (u + 0x7fffu + ((u >> 16) & 1u)) >> 16;
    return (ushort_t)u;
}

// ---------------------------------------------------------------------------
// Kernel 1: fused LayerNorm + KV projection GEMM.
//   out kv[token][0..255] = LN(feat[token]) @ Wp^T + bp    (bf16)
//   grid: (1024 m-tiles of 128 tokens, 2 n-halves of 128, 2 sides), 512 thr
// ---------------------------------------------------------------------------
__global__ __launch_bounds__(512, 4)
void k_ln_proj(const float* __restrict__ featL, const float* __restrict__ featR,
               const float* __restrict__ WL,    const float* __restrict__ WR,
               const float* __restrict__ bL,    const float* __restrict__ bR,
               const float* __restrict__ nw,    const float* __restrict__ nb,
               ushort_t* __restrict__ kvL,      ushort_t* __restrict__ kvR)
{
    const int side = blockIdx.z;
    const float* feat = side ? featR : featL;
    const float* Wp   = side ? WR    : WL;
    const float* bp   = side ? bR    : bL;
    ushort_t*    kv   = side ? kvR   : kvL;

    const int m0 = blockIdx.x * 128;   // token tile
    const int n0 = blockIdx.y * 128;   // output-feature half

    __shared__ ushort_t Asm[128][136];   // LN'd activations (bf16)
    __shared__ ushort_t Bsm[128][136];   // weight half (bf16), row = out feature
    __shared__ float    nwb[2][128];

    const int tid = threadIdx.x;
    if (tid < 128) { nwb[0][tid] = nw[tid]; nwb[1][tid] = nb[tid]; }
    __syncthreads();

    // stage W half: rows n0..n0+127 x 128 cols (f32 -> bf16)
#pragma unroll
    for (int i = 0; i < 8; ++i) {
        int u = tid + i * 512;           // float4 units, 32 per row
        int r = u >> 5;
        int c4 = (u & 31) * 4;
        float4 w4 = *(const float4*)(Wp + (size_t)(n0 + r) * CC + c4);
        Bsm[r][c4 + 0] = f2bf(w4.x);
        Bsm[r][c4 + 1] = f2bf(w4.y);
        Bsm[r][c4 + 2] = f2bf(w4.z);
        Bsm[r][c4 + 3] = f2bf(w4.w);
    }

    // LayerNorm: 128 rows, 4 threads/row, 32 elems each
    {
        const int row = tid >> 2;
        const int q   = tid & 3;
        float x[32];
        const float* fr = feat + (size_t)(m0 + row) * CC + q * 32;
        float s = 0.f, s2 = 0.f;
#pragma unroll
        for (int i = 0; i < 8; ++i) {
            float4 v = *(const float4*)(fr + i * 4);
            x[i*4+0] = v.x; x[i*4+1] = v.y; x[i*4+2] = v.z; x[i*4+3] = v.w;
            s  += v.x + v.y + v.z + v.w;
            s2 += v.x*v.x + v.y*v.y + v.z*v.z + v.w*v.w;
        }
#pragma unroll
        for (int m = 1; m < 4; m <<= 1) { s += __shfl_xor(s, m); s2 += __shfl_xor(s2, m); }
        float mu   = s * (1.f / 128.f);
        float var  = s2 * (1.f / 128.f) - mu * mu;
        float rstd = rsqrtf(var + 1e-5f);
#pragma unroll
        for (int i = 0; i < 32; ++i) {
            int c = q * 32 + i;
            float v = (x[i] - mu) * rstd * nwb[0][c] + nwb[1][c];
            Asm[row][c] = f2bf(v);
        }
    }
    __syncthreads();

    // MFMA: 8 waves = 4m x 2n, wave tile 32x64
    const int wid = tid >> 6, lane = tid & 63, l16 = lane & 15, lh = lane >> 4;
    const int wm = (wid >> 1) * 32;
    const int wn = (wid & 1) * 64;
    f32x4 acc[2][4];
#pragma unroll
    for (int tr = 0; tr < 2; ++tr)
#pragma unroll
        for (int tn = 0; tn < 4; ++tn)
            acc[tr][tn] = (f32x4){0.f, 0.f, 0.f, 0.f};

#pragma unroll
    for (int kk = 0; kk < 4; ++kk) {
        short8 a[2], b[4];
#pragma unroll
        for (int tr = 0; tr < 2; ++tr)
            a[tr] = *(const short8*)&Asm[wm + tr*16 + l16][kk*32 + lh*8];
#pragma unroll
        for (int tn = 0; tn < 4; ++tn)
            b[tn] = *(const short8*)&Bsm[wn + tn*16 + l16][kk*32 + lh*8];
#pragma unroll
        for (int tr = 0; tr < 2; ++tr)
#pragma unroll
            for (int tn = 0; tn < 4; ++tn)
                acc[tr][tn] = mfma16(a[tr], b[tn], acc[tr][tn]);
    }

#pragma unroll
    for (int tr = 0; tr < 2; ++tr)
#pragma unroll
        for (int tn = 0; tn < 4; ++tn) {
            int ccol = n0 + wn + tn*16 + l16;
            float bias = bp[ccol];
#pragma unroll
            for (int j = 0; j < 4; ++j) {
                int rrow = m0 + wm + tr*16 + lh*4 + j;
                kv[(size_t)rrow * 256 + ccol] = f2bf(acc[tr][tn][j] + bias);
            }
        }
}

// ---------------------------------------------------------------------------
// Kernel 2: attention for one direction.
//   S[w,v] = kA[w,:] . kB[v,:] ;  P = softmax_v(0.1*S) ; out[w,:] = P @ V
//   kA from kvA k-half, kB + V from kvB.  One block per (batch n, head e).
//   out is f32 [token][128] (a half of d_out used as scratch).
// ---------------------------------------------------------------------------
__global__ __launch_bounds__(512, 2)
void k_attn(const ushort_t* __restrict__ kvA, const ushort_t* __restrict__ kvB,
            float* __restrict__ out)
{
    const int n = blockIdx.x >> 2;
    const int e = blockIdx.x & 3;
    const int tid = threadIdx.x;

    __shared__ ushort_t kA[256][40];
    __shared__ ushort_t kB[256][40];
    __shared__ ushort_t vT[32][264];      // transposed V: [c][v]
    __shared__ ushort_t pL[8][32][40];    // wave-private P chunk

    // stage kA, kB (256x32 bf16 each)
#pragma unroll
    for (int p = 0; p < 2; ++p) {
        int u = tid + p * 512;            // 0..1023, 4 x 8-elem chunks per row
        int r = u >> 2, c0 = (u & 3) * 8;
        size_t off = (size_t)(n * 256 + r) * 256 + e * 32 + c0;
        *(i32x4*)&kA[r][c0] = *(const i32x4*)(kvA + off);
        *(i32x4*)&kB[r][c0] = *(const i32x4*)(kvB + off);
    }
    // stage V transposed
#pragma unroll
    for (int i = 0; i < 8; ++i) {
        int u = tid + i * 512;            // 0..4095 u32 units
        int v = u >> 4, cp = u & 15;
        unsigned int w = *(const unsigned int*)(kvB + (size_t)(n * 256 + v) * 256 + 128 + e * 32 + cp * 2);
        vT[2*cp    ][v] = (ushort_t)(w & 0xffffu);
        vT[2*cp + 1][v] = (ushort_t)(w >> 16);
    }
    __syncthreads();

    const int wid = tid >> 6, lane = tid & 63, l16 = lane & 15, lh = lane >> 4;

    // S = kA(stripe) @ kB^T : wave handles rows wid*32..+31, all 256 cols
    short8 aK[2];
#pragma unroll
    for (int tr = 0; tr < 2; ++tr)
        aK[tr] = *(const short8*)&kA[wid*32 + tr*16 + l16][lh*8];

    f32x4 acc[2][16];
#pragma unroll
    for (int tr = 0; tr < 2; ++tr)
#pragma unroll
        for (int tc = 0; tc < 16; ++tc)
            acc[tr][tc] = (f32x4){0.f, 0.f, 0.f, 0.f};

#pragma unroll
    for (int tc = 0; tc < 16; ++tc) {
        short8 b = *(const short8*)&kB[tc*16 + l16][lh*8];
        acc[0][tc] = mfma16(aK[0], b, acc[0][tc]);
        acc[1][tc] = mfma16(aK[1], b, acc[1][tc]);
    }

    // row softmax over v (scale 0.1 folded into exp)
    float rinv[2][4];
#pragma unroll
    for (int tr = 0; tr < 2; ++tr)
#pragma unroll
        for (int j = 0; j < 4; ++j) {
            float m = -1e30f;
#pragma unroll
            for (int tc = 0; tc < 16; ++tc) m = fmaxf(m, acc[tr][tc][j]);
#pragma unroll
            for (int msk = 1; msk < 16; msk <<= 1) m = fmaxf(m, __shfl_xor(m, msk));
            float sum = 0.f;
#pragma unroll
            for (int tc = 0; tc < 16; ++tc) {
                float p = __expf(0.1f * (acc[tr][tc][j] - m));
                acc[tr][tc][j] = p;
                sum += p;
            }
#pragma unroll
            for (int msk = 1; msk < 16; msk <<= 1) sum += __shfl_xor(sum, msk);
            rinv[tr][j] = 1.f / sum;
        }

    // PV: loop over 8 v-chunks of 32; stage P chunk in wave-private LDS
    f32x4 oacc[2][2];
#pragma unroll
    for (int tr = 0; tr < 2; ++tr)
#pragma unroll
        for (int nt = 0; nt < 2; ++nt)
            oacc[tr][nt] = (f32x4){0.f, 0.f, 0.f, 0.f};

#pragma unroll
    for (int ks = 0; ks < 8; ++ks) {
#pragma unroll
        for (int tr = 0; tr < 2; ++tr)
#pragma unroll
            for (int t = 0; t < 2; ++t) {
                int tc = ks * 2 + t;
#pragma unroll
                for (int j = 0; j < 4; ++j) {
                    float pv = acc[tr][tc][j] * rinv[tr][j];
                    pL[wid][tr*16 + lh*4 + j][t*16 + l16] = f2bf(pv);
                }
            }
        short8 aP[2], bV[2];
#pragma unroll
        for (int tr = 0; tr < 2; ++tr)
            aP[tr] = *(const short8*)&pL[wid][tr*16 + l16][lh*8];
#pragma unroll
        for (int nt = 0; nt < 2; ++nt)
            bV[nt] = *(const short8*)&vT[nt*16 + l16][ks*32 + lh*8];
#pragma unroll
        for (int tr = 0; tr < 2; ++tr)
#pragma unroll
            for (int nt = 0; nt < 2; ++nt)
                oacc[tr][nt] = mfma16(aP[tr], bV[nt], oacc[tr][nt]);
    }

    // store f32 attention output
#pragma unroll
    for (int tr = 0; tr < 2; ++tr)
#pragma unroll
        for (int nt = 0; nt < 2; ++nt)
#pragma unroll
            for (int j = 0; j < 4; ++j) {
                int w = wid*32 + tr*16 + lh*4 + j;
                int c = nt*16 + l16;
                out[(size_t)(n * 256 + w) * CC + e * 32 + c] = oacc[tr][nt][j];
            }
}

// ---------------------------------------------------------------------------
// Kernel 3: out projection + bias + residual, in-place on d_out half.
//   io[token] = feat[token] + io[token] @ Wo^T + bo
//   grid: (2048 tiles of 64 tokens, 2 sides), 512 thr
// ---------------------------------------------------------------------------
__global__ __launch_bounds__(512, 4)
void k_outproj(float* __restrict__ outBase,
               const float* __restrict__ featL, const float* __restrict__ featR,
               const float* __restrict__ WoL,   const float* __restrict__ WoR,
               const float* __restrict__ boL,   const float* __restrict__ boR)
{
    const int side = blockIdx.y;
    float* io = outBase + (size_t)side * TOK * CC;
    const float* feat = side ? featR : featL;
    const float* Wo   = side ? WoR   : WoL;
    const float* bo   = side ? boR   : boL;

    const int m0 = blockIdx.x * 64;
    const int tid = threadIdx.x;

    __shared__ ushort_t Asm[64][136];
    __shared__ ushort_t Wsm[128][136];

    // stage Wo (128x128 f32 -> bf16)
#pragma unroll
    for (int i = 0; i < 8; ++i) {
        int u = tid + i * 512;
        int r = u >> 5, c4 = (u & 31) * 4;
        float4 w4 = *(const float4*)(Wo + (size_t)r * CC + c4);
        Wsm[r][c4+0] = f2bf(w4.x); Wsm[r][c4+1] = f2bf(w4.y);
        Wsm[r][c4+2] = f2bf(w4.z); Wsm[r][c4+3] = f2bf(w4.w);
    }
    // stage attention-out tile (f32 in io -> bf16)
#pragma unroll
    for (int i = 0; i < 4; ++i) {
        int u = tid + i * 512;
        int r = u >> 5, c4 = (u & 31) * 4;
        float4 a4 = *(const float4*)(io + (size_t)(m0 + r) * CC + c4);
        Asm[r][c4+0] = f2bf(a4.x); Asm[r][c4+1] = f2bf(a4.y);
        Asm[r][c4+2] = f2bf(a4.z); Asm[r][c4+3] = f2bf(a4.w);
    }
    __syncthreads();

    const int wid = tid >> 6, lane = tid & 63, l16 = lane & 15, lh = lane >> 4;
    const int wm = (wid >> 2) * 32;   // 2 m-waves
    const int wn = (wid & 3) * 32;    // 4 n-waves
    f32x4 acc[2][2];
#pragma unroll
    for (int tr = 0; tr < 2; ++tr)
#pragma unroll
        for (int nt = 0; nt < 2; ++nt)
            acc[tr][nt] = (f32x4){0.f, 0.f, 0.f, 0.f};

#pragma unroll
    for (int kk = 0; kk < 4; ++kk) {
        short8 a[2], b[2];
#pragma unroll
        for (int tr = 0; tr < 2; ++tr)
            a[tr] = *(const short8*)&Asm[wm + tr*16 + l16][kk*32 + lh*8];
#pragma unroll
        for (int nt = 0; nt < 2; ++nt)
            b[nt] = *(const short8*)&Wsm[wn + nt*16 + l16][kk*32 + lh*8];
#pragma unroll
        for (int tr = 0; tr < 2; ++tr)
#pragma unroll
            for (int nt = 0; nt < 2; ++nt)
                acc[tr][nt] = mfma16(a[tr], b[nt], acc[tr][nt]);
    }

#pragma unroll
    for (int tr = 0; tr < 2; ++tr)
#pragma unroll
        for (int nt = 0; nt < 2; ++nt) {
            int c = wn + nt*16 + l16;
            float bias = bo[c];
#pragma unroll
            for (int j = 0; j < 4; ++j) {
                int r = m0 + wm + tr*16 + lh*4 + j;
                io[(size_t)r * CC + c] = acc[tr][nt][j] + bias + feat[(size_t)r * CC + c];
            }
        }
}

// ---------------------------------------------------------------------------
extern "C" void kernel_launch(void* const* d_in, const int* in_sizes, int n_in,
                              void* d_out, int out_size, void* d_ws, size_t ws_size,
                              hipStream_t stream)
{
    const float* featL = (const float*)d_in[0];
    const float* featR = (const float*)d_in[1];
    const float* WpL   = (const float*)d_in[2];
    const float* WpR   = (const float*)d_in[3];
    const float* bpL   = (const float*)d_in[4];
    const float* bpR   = (const float*)d_in[5];
    const float* WoL   = (const float*)d_in[6];
    const float* boL   = (const float*)d_in[7];
    const float* WoR   = (const float*)d_in[8];
    const float* boR   = (const float*)d_in[9];
    const float* nw    = (const float*)d_in[10];
    const float* nb    = (const float*)d_in[11];

    float* out = (float*)d_out;
    ushort_t* kvL = (ushort_t*)d_ws;                     // [TOK][256] bf16
    ushort_t* kvR = kvL + (size_t)TOK * 256;             // [TOK][256] bf16
    float* outL = out;                                   // left half (scratch then final)
    float* outR = out + (size_t)TOK * CC;                // right half

    k_ln_proj<<<dim3(1024, 2, 2), 512, 0, stream>>>(featL, featR, WpL, WpR,
                                                    bpL, bpR, nw, nb, kvL, kvR);
    // left attends over right (queries = l_k, keys+values from r)
    k_attn<<<dim3(BH * NHEAD), 512, 0, stream>>>(kvL, kvR, outL);
    // right attends over left (transposed scores == swapped operands)
    k_attn<<<dim3(BH * NHEAD), 512, 0, stream>>>(kvR, kvL, outR);
    k_outproj<<<dim3(TOK / 64, 2), 512, 0, stream>>>(out, featL, featR,
                                                     WoL, WoR, boL, boR);
}